// Round 11
// baseline (32.059 us; speedup 1.0000x reference)
//
#include <hip/hip_runtime.h>

#define BIGV 1e9f
#define NPT 256            // N == M == 256

// band: |i-j| <= 51.  i-window on diagonal s:
__device__ __forceinline__ int imin_of(int s){
    int a = s - 255; if (a < 0) a = 0;            // j = s-i <= 255
    int c = s - 50;  c = (c > 0) ? (c >> 1) : 0;  // ceil((s-51)/2)
    return (a > c) ? a : c;
}
__device__ __forceinline__ int imax_of(int s){
    int a = (s < 255) ? s : 255;
    int c = (s + 51) >> 1;                        // floor((s+51)/2)
    return (a < c) ? a : c;
}

// window base for group g (rows s = 8g+1 .. 8g+8)
__device__ __forceinline__ int Wof(int g){
    int w = imin_of(8*g + 1) - 1;
    return (w < 0) ? 0 : ((w > 192) ? 192 : w);
}
__device__ __forceinline__ int wrow_of(int s){
    return (s == 0) ? 0 : Wof((s - 1) >> 3);
}

// wave-wide shift by 1 with BIG fill: lane l <- x[l-1]
__device__ __forceinline__ float dpp_shr1(float x){
    return __int_as_float(__builtin_amdgcn_update_dpp(
        __float_as_int(BIGV), __float_as_int(x), 0x138 /*WAVE_SHR1*/, 0xF, 0xF, false));
}
__device__ __forceinline__ float dpp_shl1(float x){
    return __int_as_float(__builtin_amdgcn_update_dpp(
        __float_as_int(BIGV), __float_as_int(x), 0x130 /*WAVE_SHL1*/, 0xF, 0xF, false));
}

__device__ __forceinline__ float min3f(float a, float b, float c){
    float r;
    asm("v_min3_f32 %0, %1, %2, %3" : "=v"(r) : "v"(a), "v"(b), "v"(c));
    return r;
}

// ---------------- Kernel A: banded distances -> windowed 64-float rows -----------
// (FROZEN from round 10 for clean attribution.)
__global__ __launch_bounds__(256, 1) void ldtw_dist(const float* __restrict__ X,
                                                    const float* __restrict__ Y,
                                                    float* __restrict__ Dwin)
{
    __shared__ float4 Xs[80*17];
    __shared__ float4 Ys[80*17];
    __shared__ float nX[80], nY[80];
    __shared__ float Band[32*65];   // pitch 65
    const int b  = blockIdx.x & 15;
    const int c  = blockIdx.x >> 4;       // 0..15, 32 diagonals each
    const int s0 = c << 5;
    const int s1 = (s0 + 31 > 510) ? 510 : (s0 + 31);
    const int ilo = imin_of(s0), ihi = imax_of(s1);
    const int jlo = s0 - imax_of(s0), jhi = s1 - imin_of(s1);
    const int nx = ihi - ilo + 1, ny = jhi - jlo + 1;   // each <= 68
    const int t = threadIdx.x;
    const float4* Xb = (const float4*)(X + (size_t)b * NPT * 64);
    const float4* Yb = (const float4*)(Y + (size_t)b * NPT * 64);

    for (int idx = t; idx < nx * 16; idx += 256){
        int r = idx >> 4, k = idx & 15;
        Xs[r*17 + k] = Xb[(ilo + r)*16 + k];
    }
    for (int idx = t; idx < ny * 16; idx += 256){
        int r = idx >> 4, k = idx & 15;
        Ys[r*17 + k] = Yb[(jlo + r)*16 + k];
    }
    __syncthreads();

    for (int r = t; r < nx + ny; r += 256){
        const float4* row = (r < nx) ? (Xs + r*17) : (Ys + (r - nx)*17);
        float acc = 0.f;
        #pragma unroll
        for (int k = 0; k < 16; ++k){
            float4 v = row[k];
            acc += v.x*v.x + v.y*v.y + v.z*v.z + v.w*v.w;
        }
        if (r < nx) nX[r] = acc; else nY[r - nx] = acc;
    }
    __syncthreads();

    {
        const int ti = t >> 4;       // 0..15
        const int tj = t & 15;       // 0..15
        float acc[5][5];
        #pragma unroll
        for (int u = 0; u < 5; ++u)
            #pragma unroll
            for (int v = 0; v < 5; ++v) acc[u][v] = 0.f;

        #pragma unroll 2
        for (int k = 0; k < 16; ++k){
            float4 xa[5], ya[5];
            #pragma unroll
            for (int u = 0; u < 5; ++u){
                xa[u] = Xs[(ti + u*16)*17 + k];
                ya[u] = Ys[(tj + u*16)*17 + k];
            }
            #pragma unroll
            for (int u = 0; u < 5; ++u)
                #pragma unroll
                for (int v = 0; v < 5; ++v)
                    acc[u][v] += xa[u].x*ya[v].x + xa[u].y*ya[v].y
                               + xa[u].z*ya[v].z + xa[u].w*ya[v].w;
        }

        #pragma unroll
        for (int u = 0; u < 5; ++u){
            #pragma unroll
            for (int v = 0; v < 5; ++v){
                const int iloc = ti + u*16, jloc = tj + v*16;
                const int i = ilo + iloc, j = jlo + jloc;
                const int s = i + j;
                if (s >= s0 && s <= s1){
                    const int im = imin_of(s), ix = imax_of(s);
                    if (i >= im && i <= ix)
                        Band[(s - s0)*65 + (i - im)] =
                            nX[iloc] + nY[jloc] - 2.f*acc[u][v];
                }
            }
        }
    }
    __syncthreads();

    const size_t rowbase = (size_t)(b * 512 + s0) * 64;
    for (int slot = t; slot < 32*64; slot += 256){
        const int sd = slot >> 6, l = slot & 63;
        const int s  = s0 + sd;
        float val = BIGV;
        if (s <= 510){
            const int W = wrow_of(s);
            const int i = W + l;
            const int im = imin_of(s), ix = imax_of(s);
            if (i >= im && i <= ix) val = Band[sd*65 + (i - im)];
        }
        Dwin[rowbase + (size_t)sd*64 + l] = val;
    }
}

// ---------------- Kernel B: producer-consumer DP ---------------------------------
// waves 1-3: bulk-copy next 64-row chunk of Dwin into LDS (double buffer).
// wave 0: serial DP consuming D from LDS only (never global after init).
__global__ __launch_bounds__(256, 1) void ldtw_dp(const float* __restrict__ Dw,
                                                  float* __restrict__ out)
{
    __shared__ float Dl[2*64*64];      // 32 KB, two 64-row chunks
    const int b  = blockIdx.x;
    const int t  = threadIdx.x;
    const int wv = t >> 6;
    const int l  = t & 63;

    // prologue: waves 1-3 load chunk 0 (rows 1..64) into buf 0
    if (wv != 0){
        const int r = t - 64;                          // 0..191
        const float* src = Dw + ((size_t)b*512 + 1)*64;
        #pragma unroll
        for (int k = 0; k < 22; ++k){
            int idx = r + k*192;
            if (idx < 4096) Dl[idx] = src[idx];
        }
    }
    float p = BIGV, q = BIGV;
    if (wv == 0) p = Dw[(size_t)b*512*64 + l];         // row 0 (W=0)
    __syncthreads();

#define LOADL(Pr, gi) { \
    Pr##0 = bufp[((gi)*8 + 0)*64]; Pr##1 = bufp[((gi)*8 + 1)*64]; \
    Pr##2 = bufp[((gi)*8 + 2)*64]; Pr##3 = bufp[((gi)*8 + 3)*64]; \
    Pr##4 = bufp[((gi)*8 + 4)*64]; Pr##5 = bufp[((gi)*8 + 5)*64]; \
    Pr##6 = bufp[((gi)*8 + 6)*64]; Pr##7 = bufp[((gi)*8 + 7)*64]; }

#define SHIFTG(g) { \
    int d_ = Wof(g) - Wof((g) - 1); \
    for (int k_ = 0; k_ < d_; ++k_){ p = dpp_shl1(p); q = dpp_shl1(q); } }

#define STEP_PQ(w) q = min3f(dpp_shr1(p), p, dpp_shr1(q)) + (w);
#define STEP_QP(w) p = min3f(dpp_shr1(q), q, dpp_shr1(p)) + (w);

#define GROUP8C(Pr, g) { SHIFTG(g) \
    STEP_PQ(Pr##0) STEP_QP(Pr##1) STEP_PQ(Pr##2) STEP_QP(Pr##3) \
    STEP_PQ(Pr##4) STEP_QP(Pr##5) STEP_PQ(Pr##6) STEP_QP(Pr##7) }

#define GROUP6C(Pr, g) { SHIFTG(g) \
    STEP_PQ(Pr##0) STEP_QP(Pr##1) STEP_PQ(Pr##2) STEP_QP(Pr##3) \
    STEP_PQ(Pr##4) STEP_QP(Pr##5) }

    for (int cc = 0; cc < 8; ++cc){
        if (wv == 0){
            const float* bufp = Dl + ((cc & 1) << 12) + l;
            const int g0 = cc << 3;
            float A0,A1,A2,A3,A4,A5,A6,A7;
            float B0,B1,B2,B3,B4,B5,B6,B7;
            LOADL(A, 0)
            LOADL(B, 1)  GROUP8C(A, g0 + 0)
            LOADL(A, 2)  GROUP8C(B, g0 + 1)
            LOADL(B, 3)  GROUP8C(A, g0 + 2)
            LOADL(A, 4)  GROUP8C(B, g0 + 3)
            LOADL(B, 5)  GROUP8C(A, g0 + 4)
            LOADL(A, 6)  GROUP8C(B, g0 + 5)
            LOADL(B, 7)  GROUP8C(A, g0 + 6)
            if (cc < 7){ GROUP8C(B, g0 + 7) }
            else       { GROUP6C(B, 63) }          // s = 505..510
        } else if (cc < 7){
            const int r = t - 64;
            float* dst = Dl + (((cc + 1) & 1) << 12);
            const float* src = Dw + ((size_t)b*512 + 64*(cc + 1) + 1)*64;
            const int lim = (cc == 6) ? 4032 : 4096;   // chunk 7 ends at row 511
            #pragma unroll
            for (int k = 0; k < 22; ++k){
                int idx = r + k*192;
                if (idx < lim) dst[idx] = src[idx];
                else if (idx < 4096) dst[idx] = BIGV;
            }
        }
        __syncthreads();
    }

    if (t == 63) out[b] = p;               // dp[510][255]
#undef LOADL
#undef SHIFTG
#undef STEP_PQ
#undef STEP_QP
#undef GROUP8C
#undef GROUP6C
}

// ---------------- Fallback (tiny ws): fused, D on the fly ----------------
__device__ __forceinline__ float cell_d(const float4* __restrict__ Xb,
                                        const float4* __restrict__ Yb,
                                        int i, int j)
{
    const float4* xr = Xb + i*16;
    const float4* yr = Yb + j*16;
    float acc = 0.f;
    #pragma unroll
    for (int k = 0; k < 16; ++k){
        float4 a = xr[k], bb = yr[k];
        float dx = a.x-bb.x, dy = a.y-bb.y, dz = a.z-bb.z, dw = a.w-bb.w;
        acc += dx*dx + dy*dy + dz*dz + dw*dw;
    }
    return acc;
}

__global__ __launch_bounds__(64) void ldtw_fused_fb(const float* __restrict__ X,
                                                    const float* __restrict__ Y,
                                                    float* __restrict__ out)
{
    const int b = blockIdx.x;
    const int l = threadIdx.x;
    const float4* Xb = (const float4*)(X + (size_t)b * NPT * 64);
    const float4* Yb = (const float4*)(Y + (size_t)b * NPT * 64);
    float prev1 = (l == 0) ? cell_d(Xb, Yb, 0, 0) : BIGV;
    float prev2 = BIGV;
    int base1 = 0, base2 = 0;
    for (int s = 1; s <= 510; ++s){
        const int im = imin_of(s);
        const int ix = imax_of(s);
        const int i  = im + l;
        const bool act = (i <= ix);
        const int ic = act ? i : ix;
        const int j  = s - ic;
        float Dv = cell_d(Xb, Yb, ic, j);
        const int d1 = im - base1, d2 = im - base2;
        float sr1 = dpp_shr1(prev1), sl1 = dpp_shl1(prev1);
        float sr2 = dpp_shr1(prev2), sl2 = dpp_shl1(prev2);
        float m1 = d1 ? fminf(prev1, sl1) : fminf(sr1, prev1);
        float vd = (d2 == 0) ? sr2 : ((d2 == 2) ? sl2 : prev2);
        float m3 = fminf(m1, vd);
        float cur = act ? (m3 + Dv) : BIGV;
        prev2 = prev1; base2 = base1;
        prev1 = cur;   base1 = im;
    }
    if (l == 0) out[b] = prev1;
}

extern "C" void kernel_launch(void* const* d_in, const int* in_sizes, int n_in,
                              void* d_out, int out_size, void* d_ws, size_t ws_size,
                              hipStream_t stream)
{
    const float* X = (const float*)d_in[0];
    const float* Y = (const float*)d_in[1];
    float* out = (float*)d_out;
    const int Bn = in_sizes[0] / (NPT * 64);     // = 16
    const size_t need = (size_t)Bn * 512 * 64 * 4 + 65536;
    if (ws_size >= need && Bn == 16){
        float* Dwin = (float*)d_ws;
        hipLaunchKernelGGL(ldtw_dist, dim3(256), dim3(256), 0, stream, X, Y, Dwin);
        hipLaunchKernelGGL(ldtw_dp,   dim3(Bn),  dim3(256), 0, stream, Dwin, out);
    } else {
        hipLaunchKernelGGL(ldtw_fused_fb, dim3(Bn), dim3(64), 0, stream, X, Y, out);
    }
}